// Round 1
// baseline (223.221 us; speedup 1.0000x reference)
//
#include <hip/hip_runtime.h>

// ReLU over fp32, memory-bound. Vectorized float4 (16 B/lane), grid-stride.
// n = 32*4096*1024 = 134,217,728 (divisible by 4, but tail handled anyway).

__global__ void relu_f4_kernel(const float4* __restrict__ in,
                               float4* __restrict__ out,
                               long long n4) {
    long long idx = (long long)blockIdx.x * blockDim.x + threadIdx.x;
    long long stride = (long long)gridDim.x * blockDim.x;
    for (long long i = idx; i < n4; i += stride) {
        float4 v = in[i];
        v.x = v.x > 0.0f ? v.x : 0.0f;
        v.y = v.y > 0.0f ? v.y : 0.0f;
        v.z = v.z > 0.0f ? v.z : 0.0f;
        v.w = v.w > 0.0f ? v.w : 0.0f;
        out[i] = v;
    }
}

__global__ void relu_tail_kernel(const float* __restrict__ in,
                                 float* __restrict__ out,
                                 long long start, long long n) {
    long long i = start + (long long)blockIdx.x * blockDim.x + threadIdx.x;
    if (i < n) {
        float v = in[i];
        out[i] = v > 0.0f ? v : 0.0f;
    }
}

extern "C" void kernel_launch(void* const* d_in, const int* in_sizes, int n_in,
                              void* d_out, int out_size, void* d_ws, size_t ws_size,
                              hipStream_t stream) {
    const float* x = (const float*)d_in[0];
    float* y = (float*)d_out;
    long long n = (long long)in_sizes[0];

    long long n4 = n / 4;
    const int block = 256;
    // Cap grid at ~2048 blocks (256 CU x 8 blocks/CU), grid-stride the rest.
    long long want = (n4 + block - 1) / block;
    int grid = (int)(want < 2048 ? (want > 0 ? want : 1) : 2048);

    if (n4 > 0) {
        relu_f4_kernel<<<grid, block, 0, stream>>>(
            (const float4*)x, (float4*)y, n4);
    }

    long long tail_start = n4 * 4;
    long long tail = n - tail_start;
    if (tail > 0) {
        int tgrid = (int)((tail + block - 1) / block);
        relu_tail_kernel<<<tgrid, block, 0, stream>>>(x, y, tail_start, n);
    }
}